// Round 1
// baseline (753.670 us; speedup 1.0000x reference)
//
#include <hip/hip_runtime.h>
#include <hip/hip_bf16.h>

// Problem constants
#define BB 16
#define N1 256
#define N2 256
#define FA 128
#define FE 128

typedef __attribute__((ext_vector_type(8))) short bf16x8;
typedef __attribute__((ext_vector_type(4))) float f32x4;

static __device__ __forceinline__ unsigned short f2bf(float f) {
    union { float f; unsigned int u; } v; v.f = f;
    unsigned int u = v.u;
    unsigned int r = (u + 0x7FFFu + ((u >> 16) & 1u)) >> 16;  // RNE
    return (unsigned short)r;
}

static __device__ __forceinline__ bf16x8 pack8(float4 lo, float4 hi) {
    bf16x8 r;
    r[0] = (short)f2bf(lo.x); r[1] = (short)f2bf(lo.y);
    r[2] = (short)f2bf(lo.z); r[3] = (short)f2bf(lo.w);
    r[4] = (short)f2bf(hi.x); r[5] = (short)f2bf(hi.y);
    r[6] = (short)f2bf(hi.z); r[7] = (short)f2bf(hi.w);
    return r;
}

// out[row][g] = x[row,:] @ W[:, g] + bias[g]; 8 rows per block, 128 threads.
__global__ __launch_bounds__(128) void prep_gemm(const float* __restrict__ x,
                                                 const float* __restrict__ W,
                                                 const float* __restrict__ bias,
                                                 float* __restrict__ out) {
    __shared__ float xs[8][128];
    const int r0 = blockIdx.x * 8;
    const int g = threadIdx.x;
    #pragma unroll
    for (int r = 0; r < 8; ++r)
        xs[r][g] = x[(size_t)(r0 + r) * FA + g];
    __syncthreads();
    float acc[8];
    const float bv = bias[g];
    #pragma unroll
    for (int r = 0; r < 8; ++r) acc[r] = bv;
    #pragma unroll 8
    for (int f = 0; f < 128; ++f) {
        const float wv = W[f * FA + g];
        #pragma unroll
        for (int r = 0; r < 8; ++r) acc[r] += xs[r][f] * wv;
    }
    #pragma unroll
    for (int r = 0; r < 8; ++r)
        out[(size_t)(r0 + r) * FA + g] = acc[r];
}

// Same GEMM but stores TRANSPOSED: outT[b][g][j] = x2[b,j,:]@W[:,g] + bias[g].
__global__ __launch_bounds__(128) void prep_gemm_T(const float* __restrict__ x,
                                                   const float* __restrict__ W,
                                                   const float* __restrict__ bias,
                                                   float* __restrict__ outT) {
    __shared__ float xs[8][128];
    const int r0 = blockIdx.x * 8;       // global row (b*256 + j)
    const int b = r0 >> 8;
    const int j0 = r0 & 255;
    const int g = threadIdx.x;
    #pragma unroll
    for (int r = 0; r < 8; ++r)
        xs[r][g] = x[(size_t)(r0 + r) * FA + g];
    __syncthreads();
    float acc[8];
    const float bv = bias[g];
    #pragma unroll
    for (int r = 0; r < 8; ++r) acc[r] = bv;
    #pragma unroll 8
    for (int f = 0; f < 128; ++f) {
        const float wv = W[f * FA + g];
        #pragma unroll
        for (int r = 0; r < 8; ++r) acc[r] += xs[r][f] * wv;
    }
    float4 v0 = {acc[0], acc[1], acc[2], acc[3]};
    float4 v1 = {acc[4], acc[5], acc[6], acc[7]};
    float4* dst = (float4*)&outT[(size_t)(b * 128 + g) * 256 + j0];
    dst[0] = v0;
    dst[1] = v1;
}

// Transpose + convert Mw_e (= M_w[128:,:], [e][g]) into bf16 wT[g][e].
__global__ __launch_bounds__(256) void prep_wt(const float* __restrict__ Mw,
                                               unsigned short* __restrict__ wT) {
    const int idx = blockIdx.x * 256 + threadIdx.x;  // 0..16383
    const int g = idx >> 7, e = idx & 127;
    wT[idx] = f2bf(Mw[(size_t)(FA + e) * FA + g]);
}

// Fused edge GEMM + masked max + relu(m1+m2).
// RESTRUCTURED: one block (4 waves) per (b,i). Waves split the g-dimension
// (2 of 8 g-tiles each -> bF is 32 VGPRs, was 128). The edge j-strip
// (16 rows x 128 e) is staged ONCE per block into double-buffered,
// XOR-swizzled bf16 LDS; each wave reads conflict-free A-fragments via
// ds_read_b128. Next-strip global loads issue before the current strip's
// MFMAs (1-strip prefetch). Register demand ~110 -> 3-4 waves/SIMD, no
// spills, and enough loads in flight to approach the HBM roofline.
__global__ __launch_bounds__(256, 3) void edge_main(
    const float* __restrict__ edge,
    const float* __restrict__ valid,
    const float* __restrict__ mx2bT,       // ws fp32 [b][g=128][j=256], includes M_b
    const unsigned short* __restrict__ wT, // ws bf16 [g=128][e=128]
    float* __restrict__ out)               // holds m1 on entry; final result on exit
{
    // 2 buffers x (16 rows x 128 e) bf16 = 2 x 4 KB, XOR-swizzled layout:
    // phys_byte = logical_byte ^ ((j_row & 7) << 4)
    __shared__ __align__(16) unsigned short ebuf[2][2048];

    const int tid = threadIdx.x;
    const int wv = tid >> 6;
    const int lane = tid & 63;
    const int n = lane & 15, q = lane >> 4;
    const int bi = blockIdx.x;             // 0..4095
    const int b = bi >> 8;

    // ---- B fragments for this wave's two g-tiles (t = 2*wv + tt) ----
    bf16x8 bF[2][4];
    #pragma unroll
    for (int tt = 0; tt < 2; ++tt) {
        const int t = wv * 2 + tt;
        #pragma unroll
        for (int s = 0; s < 4; ++s)
            bF[tt][s] = *(const bf16x8*)&wT[(t * 16 + n) * FE + s * 32 + q * 8];
    }

    const float* eb  = edge + (size_t)bi * (N2 * FE);
    const float* mxT = mx2bT + (size_t)b * (N2 * FA);
    const float* vb  = valid + (size_t)bi * N2;

    // ---- staging addressing: thread tid owns logical bf16 bytes [tid*16, +16)
    // of the strip = row sj, elements [se, se+8).
    const int sj = tid >> 4;               // row within strip 0..15
    const int se = (tid & 15) * 8;         // first e element
    const float* sg = eb + (size_t)sj * FE + se;
    char* ebase = (char*)&ebuf[0][0];
    const int sphys = (tid * 16) ^ ((sj & 7) << 4);   // swizzled byte off in 4KB buf

    // prologue: stage strip 0 into buffer 0
    {
        float4 v0 = *(const float4*)(sg);
        float4 v1 = *(const float4*)(sg + 4);
        *(bf16x8*)(ebase + sphys) = pack8(v0, v1);
    }
    __syncthreads();

    float runmax[2] = {-3.0e38f, -3.0e38f};

    const int lq = n * 256 + q * 16;       // logical byte of aF[0] (s=0)
    const int xsw = (n & 7) << 4;          // read-side swizzle

    for (int strip = 0; strip < 16; ++strip) {
        const int j0 = strip * 16;
        const bool more = (strip + 1) < 16;

        // issue next strip's global loads FIRST (latency hides under MFMAs)
        float4 p0, p1;
        if (more) {
            const float* nsg = sg + (size_t)(j0 + 16) * FE;
            p0 = *(const float4*)(nsg);
            p1 = *(const float4*)(nsg + 4);
        }

        // epilogue inputs (L2-resident)
        const float4 vld = *(const float4*)(vb + j0 + q * 4);
        float4 mxv[2];
        #pragma unroll
        for (int tt = 0; tt < 2; ++tt) {
            const int t = wv * 2 + tt;
            mxv[tt] = *(const float4*)(mxT + (size_t)(t * 16 + n) * N2 + j0 + q * 4);
        }

        // A fragments from swizzled LDS (conflict-free ds_read_b128)
        char* cbuf = ebase + (strip & 1) * 4096;
        bf16x8 aF[4];
        #pragma unroll
        for (int s = 0; s < 4; ++s)
            aF[s] = *(const bf16x8*)(cbuf + ((lq + s * 64) ^ xsw));

        #pragma unroll
        for (int tt = 0; tt < 2; ++tt) {
            f32x4 acc = {0.f, 0.f, 0.f, 0.f};
            #pragma unroll
            for (int s = 0; s < 4; ++s)
                acc = __builtin_amdgcn_mfma_f32_16x16x32_bf16(aF[s], bF[tt][s], acc, 0, 0, 0);
            // C layout: col(g-within-tile)=n, row(j-within-strip)=q*4+r
            float v0 = (acc[0] + mxv[tt].x) * vld.x;
            float v1 = (acc[1] + mxv[tt].y) * vld.y;
            float v2 = (acc[2] + mxv[tt].z) * vld.z;
            float v3 = (acc[3] + mxv[tt].w) * vld.w;
            runmax[tt] = fmaxf(runmax[tt], fmaxf(fmaxf(v0, v1), fmaxf(v2, v3)));
        }

        // convert + write next strip into the other buffer, then barrier
        if (more) {
            *(bf16x8*)(ebase + (((strip + 1) & 1) * 4096) + sphys) = pack8(p0, p1);
        }
        __syncthreads();
    }

    // ---- cross-q reduce + fused relu(m1 + m2) epilogue ----
    #pragma unroll
    for (int tt = 0; tt < 2; ++tt) {
        float m = runmax[tt];
        m = fmaxf(m, __shfl_xor(m, 16, 64));
        m = fmaxf(m, __shfl_xor(m, 32, 64));
        if (lane < 16) {
            const int t = wv * 2 + tt;
            const size_t o = (size_t)bi * FA + t * 16 + lane;
            out[o] = fmaxf(out[o] + m, 0.0f);
        }
    }
}

extern "C" void kernel_launch(void* const* d_in, const int* in_sizes, int n_in,
                              void* d_out, int out_size, void* d_ws, size_t ws_size,
                              hipStream_t stream) {
    const float* x1    = (const float*)d_in[0];
    const float* x2    = (const float*)d_in[1];
    const float* edge  = (const float*)d_in[2];
    const float* valid = (const float*)d_in[3];
    const float* W_w   = (const float*)d_in[4];
    const float* W_b   = (const float*)d_in[5];
    const float* M_w   = (const float*)d_in[6];
    const float* M_b   = (const float*)d_in[7];
    float* out = (float*)d_out;

    // ws layout: [0, 32768) wT bf16; [32768, 32768 + 2MB) mx2bT fp32
    unsigned short* wT = (unsigned short*)d_ws;
    float* mx2bT = (float*)((char*)d_ws + 32768);

    // m1 = x1 @ W_w + W_b  -> d_out (updated in-place by edge_main epilogue)
    prep_gemm<<<BB * N1 / 8, 128, 0, stream>>>(x1, W_w, W_b, out);
    // mx2bT[b][g][j] = x2 @ M_w[:128] + M_b (transposed store) -> ws
    prep_gemm_T<<<BB * N2 / 8, 128, 0, stream>>>(x2, M_w, M_b, mx2bT);
    // wT = bf16(M_w[128:].T)
    prep_wt<<<64, 256, 0, stream>>>(M_w, wT);
    // fused edge GEMM + masked max + relu(m1 + m2): 1 block per (b,i)
    edge_main<<<BB * N1, 256, 0, stream>>>(edge, valid, mx2bT, wT, out);
}

// Round 2
// 721.098 us; speedup vs baseline: 1.0452x; 1.0452x over previous
//
#include <hip/hip_runtime.h>
#include <hip/hip_bf16.h>

// Problem constants
#define BB 16
#define N1 256
#define N2 256
#define FA 128
#define FE 128

typedef __attribute__((ext_vector_type(8))) short bf16x8;
typedef __attribute__((ext_vector_type(4))) float f32x4;

static __device__ __forceinline__ unsigned short f2bf(float f) {
    union { float f; unsigned int u; } v; v.f = f;
    unsigned int u = v.u;
    unsigned int r = (u + 0x7FFFu + ((u >> 16) & 1u)) >> 16;  // RNE
    return (unsigned short)r;
}

static __device__ __forceinline__ bf16x8 pack8(float4 lo, float4 hi) {
    bf16x8 r;
    r[0] = (short)f2bf(lo.x); r[1] = (short)f2bf(lo.y);
    r[2] = (short)f2bf(lo.z); r[3] = (short)f2bf(lo.w);
    r[4] = (short)f2bf(hi.x); r[5] = (short)f2bf(hi.y);
    r[6] = (short)f2bf(hi.z); r[7] = (short)f2bf(hi.w);
    return r;
}

// Merged prep: blocks [0,512) -> m1 = x1@W_w + W_b into out;
//              blocks [512,1024) -> mx2bT[b][g][j] = x2@M_w[:128] + M_b (transposed);
//              blocks [1024,1152) -> wT = bf16(M_w[128:].T).
// One launch so the three independent preps run concurrently.
__global__ __launch_bounds__(128) void prep_all(
    const float* __restrict__ x1, const float* __restrict__ x2,
    const float* __restrict__ W_w, const float* __restrict__ W_b,
    const float* __restrict__ M_w, const float* __restrict__ M_b,
    float* __restrict__ out, float* __restrict__ mx2bT,
    unsigned short* __restrict__ wT) {
    const int blk = blockIdx.x;
    const int g = threadIdx.x;

    if (blk >= 1024) {
        const int idx = (blk - 1024) * 128 + g;   // 0..16383
        const int gg = idx >> 7, e = idx & 127;
        wT[idx] = f2bf(M_w[(size_t)(FA + e) * FA + gg]);
        return;
    }

    __shared__ float xs[8][128];
    const bool isT = (blk >= 512);
    const int r0 = (isT ? blk - 512 : blk) * 8;   // global row (b*256 + row)
    const float* x = isT ? x2 : x1;
    const float* W = isT ? M_w : W_w;             // M_w[:128] rows used for isT
    const float* bias = isT ? M_b : W_b;

    #pragma unroll
    for (int r = 0; r < 8; ++r)
        xs[r][g] = x[(size_t)(r0 + r) * FA + g];
    __syncthreads();
    float acc[8];
    const float bv = bias[g];
    #pragma unroll
    for (int r = 0; r < 8; ++r) acc[r] = bv;
    #pragma unroll 8
    for (int f = 0; f < 128; ++f) {
        const float wv = W[f * FA + g];
        #pragma unroll
        for (int r = 0; r < 8; ++r) acc[r] += xs[r][f] * wv;
    }
    if (!isT) {
        #pragma unroll
        for (int r = 0; r < 8; ++r)
            out[(size_t)(r0 + r) * FA + g] = acc[r];
    } else {
        const int b = r0 >> 8, j0 = r0 & 255;
        float4 v0 = {acc[0], acc[1], acc[2], acc[3]};
        float4 v1 = {acc[4], acc[5], acc[6], acc[7]};
        float4* dst = (float4*)&mx2bT[(size_t)(b * 128 + g) * 256 + j0];
        dst[0] = v0;
        dst[1] = v1;
    }
}

// Fused edge GEMM + masked max + relu(m1+m2).
// One block (4 waves) per (b,i); waves split g (2 of 8 g-tiles each).
// 32-row j-strips double-buffered in XOR-swizzled bf16 LDS (2 x 8 KB):
//   - loads for strip s+1 issue at the TOP of strip s,
//   - LDS write happens at the BOTTOM (write-late): prefetch window spans
//     both 16-row MFMA sub-phases (~700 cyc) -> HBM latency hidden,
//   - one barrier per 32 rows (8 total, was 16).
// Occupancy 4 blocks/CU (VGPR ~110 <= 128).
__global__ __launch_bounds__(256, 4) void edge_main(
    const float* __restrict__ edge,
    const float* __restrict__ valid,
    const float* __restrict__ mx2bT,       // ws fp32 [b][g=128][j=256], includes M_b
    const unsigned short* __restrict__ wT, // ws bf16 [g=128][e=128]
    float* __restrict__ out)               // holds m1 on entry; final result on exit
{
    // 2 buffers x (32 rows x 128 e) bf16, XOR-swizzled:
    // phys_byte = logical_byte ^ ((j_row & 7) << 4)
    __shared__ __align__(16) unsigned short ebuf[2][4096];

    const int tid = threadIdx.x;
    const int wv = tid >> 6;
    const int lane = tid & 63;
    const int n = lane & 15, q = lane >> 4;
    const int bi = blockIdx.x;             // 0..4095
    const int b = bi >> 8;

    // ---- B fragments for this wave's two g-tiles (t = 2*wv + tt) ----
    bf16x8 bF0[4], bF1[4];
    #pragma unroll
    for (int s = 0; s < 4; ++s) {
        bF0[s] = *(const bf16x8*)&wT[((wv * 2 + 0) * 16 + n) * FE + s * 32 + q * 8];
        bF1[s] = *(const bf16x8*)&wT[((wv * 2 + 1) * 16 + n) * FE + s * 32 + q * 8];
    }

    const float* eb  = edge + (size_t)bi * (N2 * FE);
    const float* mxT = mx2bT + (size_t)b * (N2 * FA);
    const float* vb  = valid + (size_t)bi * N2;

    // ---- staging addressing: thread owns row sj (and sj+16) of the 32-row
    // strip, bf16 elements [se, se+8) of each.
    const int sj = tid >> 4;               // 0..15
    const int se = (tid & 15) * 8;
    const float* sg = eb + (size_t)sj * FE + se;
    char* ebase = (char*)&ebuf[0][0];
    const int sw = (sj & 7) << 4;
    const int sbyte0 = sj * 256 + (tid & 15) * 16;
    const int sp0 = sbyte0 ^ sw;                  // half 0 (rows 0..15)
    const int sp1 = (4096 + sbyte0) ^ sw;         // half 1 (rows 16..31)

    // prologue: stage strip 0 into buffer 0
    {
        float4 a0 = *(const float4*)(sg);
        float4 a1 = *(const float4*)(sg + 4);
        float4 b0 = *(const float4*)(sg + 16 * FE);
        float4 b1 = *(const float4*)(sg + 16 * FE + 4);
        *(bf16x8*)(ebase + sp0) = pack8(a0, a1);
        *(bf16x8*)(ebase + sp1) = pack8(b0, b1);
    }
    __syncthreads();

    float runmax0 = -3.0e38f, runmax1 = -3.0e38f;
    const int lqb = n * 256 + q * 16;      // logical byte of aF[0] within a half
    const int xsw = (n & 7) << 4;          // read-side swizzle

    for (int strip = 0; strip < 8; ++strip) {
        const bool more = (strip + 1) < 8;
        const int j0 = strip * 32;

        // issue next strip's global loads FIRST (consumed only at the bottom)
        float4 pa0, pa1, pb0, pb1;
        if (more) {
            const float* ns = sg + (size_t)(j0 + 32) * FE;
            pa0 = *(const float4*)(ns);
            pa1 = *(const float4*)(ns + 4);
            pb0 = *(const float4*)(ns + 16 * FE);
            pb1 = *(const float4*)(ns + 16 * FE + 4);
        }

        char* cbuf = ebase + (strip & 1) * 8192;

        #pragma unroll
        for (int h = 0; h < 2; ++h) {
            const int jh = j0 + h * 16;
            // epilogue inputs (L2-resident)
            const float4 vld = *(const float4*)(vb + jh + q * 4);
            const float4 mxv0 = *(const float4*)(mxT + (size_t)((wv * 2 + 0) * 16 + n) * N2 + jh + q * 4);
            const float4 mxv1 = *(const float4*)(mxT + (size_t)((wv * 2 + 1) * 16 + n) * N2 + jh + q * 4);

            // A fragments from swizzled LDS (conflict-free ds_read_b128)
            bf16x8 aF[4];
            #pragma unroll
            for (int s = 0; s < 4; ++s)
                aF[s] = *(const bf16x8*)(cbuf + ((h * 4096 + lqb + s * 64) ^ xsw));

            f32x4 acc0 = {0.f, 0.f, 0.f, 0.f};
            f32x4 acc1 = {0.f, 0.f, 0.f, 0.f};
            #pragma unroll
            for (int s = 0; s < 4; ++s) {
                acc0 = __builtin_amdgcn_mfma_f32_16x16x32_bf16(aF[s], bF0[s], acc0, 0, 0, 0);
                acc1 = __builtin_amdgcn_mfma_f32_16x16x32_bf16(aF[s], bF1[s], acc1, 0, 0, 0);
            }
            // C layout: col(g-within-tile)=n, row(j-within-strip)=q*4+r
            {
                float v0 = (acc0[0] + mxv0.x) * vld.x;
                float v1 = (acc0[1] + mxv0.y) * vld.y;
                float v2 = (acc0[2] + mxv0.z) * vld.z;
                float v3 = (acc0[3] + mxv0.w) * vld.w;
                runmax0 = fmaxf(runmax0, fmaxf(fmaxf(v0, v1), fmaxf(v2, v3)));
            }
            {
                float v0 = (acc1[0] + mxv1.x) * vld.x;
                float v1 = (acc1[1] + mxv1.y) * vld.y;
                float v2 = (acc1[2] + mxv1.z) * vld.z;
                float v3 = (acc1[3] + mxv1.w) * vld.w;
                runmax1 = fmaxf(runmax1, fmaxf(fmaxf(v0, v1), fmaxf(v2, v3)));
            }
        }

        // write-late: convert + store next strip, then barrier
        if (more) {
            char* obuf = ebase + ((strip + 1) & 1) * 8192;
            *(bf16x8*)(obuf + sp0) = pack8(pa0, pa1);
            *(bf16x8*)(obuf + sp1) = pack8(pb0, pb1);
            __syncthreads();
        }
    }

    // ---- cross-q reduce + fused relu(m1 + m2) epilogue ----
    {
        float m = runmax0;
        m = fmaxf(m, __shfl_xor(m, 16, 64));
        m = fmaxf(m, __shfl_xor(m, 32, 64));
        if (lane < 16) {
            const size_t o = (size_t)bi * FA + (wv * 2 + 0) * 16 + lane;
            out[o] = fmaxf(out[o] + m, 0.0f);
        }
    }
    {
        float m = runmax1;
        m = fmaxf(m, __shfl_xor(m, 16, 64));
        m = fmaxf(m, __shfl_xor(m, 32, 64));
        if (lane < 16) {
            const size_t o = (size_t)bi * FA + (wv * 2 + 1) * 16 + lane;
            out[o] = fmaxf(out[o] + m, 0.0f);
        }
    }
}

extern "C" void kernel_launch(void* const* d_in, const int* in_sizes, int n_in,
                              void* d_out, int out_size, void* d_ws, size_t ws_size,
                              hipStream_t stream) {
    const float* x1    = (const float*)d_in[0];
    const float* x2    = (const float*)d_in[1];
    const float* edge  = (const float*)d_in[2];
    const float* valid = (const float*)d_in[3];
    const float* W_w   = (const float*)d_in[4];
    const float* W_b   = (const float*)d_in[5];
    const float* M_w   = (const float*)d_in[6];
    const float* M_b   = (const float*)d_in[7];
    float* out = (float*)d_out;

    // ws layout: [0, 32768) wT bf16; [32768, 32768 + 2MB) mx2bT fp32
    unsigned short* wT = (unsigned short*)d_ws;
    float* mx2bT = (float*)((char*)d_ws + 32768);

    // all three preps in one launch (concurrent): m1 -> out, mx2bT -> ws, wT -> ws
    prep_all<<<1152, 128, 0, stream>>>(x1, x2, W_w, W_b, M_w, M_b, out, mx2bT, wT);
    // fused edge GEMM + masked max + relu(m1 + m2): 1 block per (b,i)
    edge_main<<<BB * N1, 256, 0, stream>>>(edge, valid, mx2bT, wT, out);
}